// Round 7
// baseline (238.171 us; speedup 1.0000x reference)
//
#include <hip/hip_runtime.h>
#include <hip/hip_bf16.h>

typedef __bf16 bf16;
typedef __bf16 bf16x8 __attribute__((ext_vector_type(8)));
typedef float f32x4 __attribute__((ext_vector_type(4)));

#define BB 64
#define EMB 256
#define UNITS 512
#define POI 5000
#define KCAT 1280
#define SCLD 5024   // sc row stride (5000 padded to x32)
#define NSPL 8      // vscore u-splits / slabs
#define L2E 1.4426950408889634f

__device__ __forceinline__ float rcp_(float x){ return __builtin_amdgcn_rcpf(x); }
__device__ __forceinline__ float exp2_(float x){ return __builtin_amdgcn_exp2f(x); }

// ---- one 16x16x(K) MFMA C-tile from fp32 sources, on-the-fly bf16 cvt.
// A fp32 row-major [*, lda]: lane -> A[mr][q*8+j]. B fp32 row-major [K, ldb]: lane -> B[q*8+j][nc].
// C/D: col=lane&15, row=q*4+reg (validated R3-R6).
__device__ __forceinline__ f32x4 mm16f(const float* __restrict__ A, const float* __restrict__ B,
                                       int lda, int ldb, int K, int mr, int nc, int lane){
  int q = lane >> 4;
  f32x4 acc = {0.f,0.f,0.f,0.f};
  const float* ap = A + (size_t)mr*lda + q*8;
  const float* bp = B + (size_t)(q*8)*ldb + nc;
#pragma unroll 2
  for(int k0 = 0; k0 < K; k0 += 32){
    f32x4 a0 = *(const f32x4*)ap;
    f32x4 a1 = *(const f32x4*)(ap+4);
    bf16x8 a, b;
#pragma unroll
    for(int j=0;j<4;j++){ a[j] = (bf16)a0[j]; a[4+j] = (bf16)a1[j]; }
#pragma unroll
    for(int j=0;j<8;j++) b[j] = (bf16)bp[(size_t)j*ldb];
    acc = __builtin_amdgcn_mfma_f32_16x16x32_bf16(a, b, acc, 0, 0, 0);
    ap += 32; bp += (size_t)32*ldb;
  }
  return acc;
}

// ---- merged GRU GEMMs, split-K x2, x1 gather inlined. grid (96, 2, 2).
// y: 0 = x1@gruK (x1 = [emb[x[m]] | query[m]]), 1 = h0@gruR. z: k-half (256 each).
__global__ __launch_bounds__(256) void k_gru(const int* __restrict__ x,
    const float* __restrict__ query, const float* __restrict__ emb, const float* __restrict__ h0,
    const float* __restrict__ gruK, const float* __restrict__ gruR,
    float* __restrict__ xmP, float* __restrict__ hmP){
  int lane = threadIdx.x & 63, w = threadIdx.x >> 6;
  int col = blockIdx.x*16 + (lane & 15);
  int m = w*16 + (lane & 15);
  int z = blockIdx.z;
  const float* A; const float* B; int lda, mr;
  if(blockIdx.y == 0){
    B = gruK + (size_t)(z*256)*1536;
    if(z == 0){ A = emb;   mr = x[m]; lda = EMB; }   // emb[x[m]][0:256]
    else      { A = query; mr = m;    lda = 256; }   // query[m][0:256]
  } else {
    B = gruR + (size_t)(z*256)*1536;
    A = h0 + z*256; mr = m; lda = UNITS;
  }
  f32x4 acc = mm16f(A, B, lda, 1536, 256, mr, col, lane);
  float* C = (blockIdx.y ? hmP : xmP) + (size_t)z*BB*1536;
  int rb = w*16 + (lane >> 4)*4;
#pragma unroll
  for(int r=0;r<4;r++) C[(size_t)(rb+r)*1536 + col] = acc[r];
}

// ---- GRU gates (keras reset_after=True, z/r/h); sums 2 k-split slabs; copies cat_dec;
// also zeroes this batch-row's logits accumulator region of d_out (replaces memset dispatch).
__global__ void k_gates(const float* __restrict__ xmP, const float* __restrict__ hmP,
                        const float* __restrict__ bias, const float* __restrict__ h0,
                        const float* __restrict__ catd,
                        float* __restrict__ hn, float* __restrict__ outc, float* __restrict__ dout){
  int b = blockIdx.x, u = threadIdx.x;  // 512 thr
  for(int p=u;p<POI;p+=512) dout[(size_t)b*POI + p] = 0.f;   // zero logits row b
  const float* x0 = xmP + b*1536; const float* x1s = xmP + (size_t)BB*1536 + b*1536;
  const float* h0s = hmP + b*1536; const float* h1s = hmP + (size_t)BB*1536 + b*1536;
  float xz = x0[u]      + x1s[u]      + bias[u];
  float xg = x0[512+u]  + x1s[512+u]  + bias[512+u];
  float xh = x0[1024+u] + x1s[1024+u] + bias[1024+u];
  float hz = h0s[u]      + h1s[u]      + bias[1536+u];
  float hg = h0s[512+u]  + h1s[512+u]  + bias[2048+u];
  float hh = h0s[1024+u] + h1s[1024+u] + bias[2560+u];
  float z = rcp_(1.f + exp2_(-L2E*(xz+hz)));
  float r = rcp_(1.f + exp2_(-L2E*(xg+hg)));
  float ca = xh + r*hh;
  ca = fminf(fmaxf(ca, -15.f), 15.f);
  float e = exp2_(2.f*L2E*ca);
  float hc = (e - 1.f)*rcp_(e + 1.f);
  float h = h0[b*512+u];
  float v = z*h + (1.f - z)*hc;
  hn[b*512+u] = v;
  outc[b*KCAT + 256 + u] = v;
  outc[b*KCAT + 768 + u] = catd[(size_t)b*512 + u];
  dout[(size_t)POI*BB + (size_t)b*512 + u] = v;                       // state
  dout[(size_t)POI*BB + (size_t)BB*512 + (size_t)b*512 + u] = v;      // output_
}

// ---- Eq = exp2(clamp(2*log2e*(hn@W2 + b2), +-28)) : [64,512]. grid 128 x 64thr (1 tile/block).
__global__ __launch_bounds__(64) void k_qproj(const float* __restrict__ hn, const float* __restrict__ W2,
                        const float* __restrict__ W2b, float* __restrict__ Eq){
  int lane = threadIdx.x;
  int m0 = (blockIdx.x & 3)*16;
  int col = (blockIdx.x >> 2)*16 + (lane & 15);
  f32x4 acc = mm16f(hn, W2, UNITS, UNITS, UNITS, m0 + (lane & 15), col, lane);
  float bn = W2b[col];
  int rb = m0 + (lane >> 4)*4;
#pragma unroll
  for(int r=0;r<4;r++){
    float v = (acc[r] + bn)*(2.f*L2E);
    Eq[(rb+r)*UNITS + col] = exp2_(fminf(fmaxf(v, -28.f), 28.f));
  }
}

// ---- fused vproj+score, grid (313, 8): 16 poi rows x 64-u eighth per block.
// stage1 MFMA -> Ev eighth in LDS; stage2 (R5 loop shape, 44-VGPR proven):
// sc_y[b][p] = sum_u Vw[u]/(Ev[p][u]*Eq[b][u]+1)  -> slab y (no atomics)
__global__ __launch_bounds__(256) void k_vscore(const float* __restrict__ emb, const float* __restrict__ W1,
    const float* __restrict__ W1b, const float* __restrict__ Eq,
    const float* __restrict__ Vw, float* __restrict__ scS){
  __shared__ float evs[16][68];
  __shared__ float Qs[64][68];
  __shared__ float vws[64];
  int t = threadIdx.x, lane = t & 63, w = t >> 6;
  int p0 = blockIdx.x*16, uh = blockIdx.y*64;
  int mr = p0 + (lane & 15); if(mr > POI-1) mr = POI-1;   // tail clamp
  {
    int ncl = w*16 + (lane & 15);                          // 4 waves x 16 = 64 local cols
    f32x4 acc = mm16f(emb, W1, EMB, UNITS, EMB, mr, uh + ncl, lane);
    float bn = W1b[uh + ncl];
    int rb = (lane >> 4)*4;
#pragma unroll
    for(int r=0;r<4;r++){
      float v = (acc[r] + bn)*(2.f*L2E);
      evs[rb+r][ncl] = exp2_(fminf(fmaxf(v, -28.f), 28.f));
    }
  }
  for(int i=t;i<4096;i+=256){ int b=i>>6, u=i&63; Qs[b][u] = Eq[b*UNITS + uh + u]; }
  if(t < 64) vws[t] = Vw[uh + t];
  __syncthreads();
  int tp = t & 7, tb = t >> 3;
  float s00=0.f, s01=0.f, s10=0.f, s11=0.f;
#pragma unroll
  for(int u4=0;u4<16;u4++){
    f32x4 e0 = *(f32x4*)&evs[2*tp][u4*4];
    f32x4 e1 = *(f32x4*)&evs[2*tp+1][u4*4];
    f32x4 q0 = *(f32x4*)&Qs[2*tb][u4*4];
    f32x4 q1 = *(f32x4*)&Qs[2*tb+1][u4*4];
    f32x4 w4 = *(f32x4*)&vws[u4*4];
#pragma unroll
    for(int e=0;e<4;e++){
      float wv = w4[e];
      s00 += wv * rcp_(e0[e]*q0[e] + 1.f);
      s01 += wv * rcp_(e0[e]*q1[e] + 1.f);
      s10 += wv * rcp_(e1[e]*q0[e] + 1.f);
      s11 += wv * rcp_(e1[e]*q1[e] + 1.f);
    }
  }
  float* s = scS + (size_t)blockIdx.y*BB*SCLD;
  int pA = p0 + 2*tp, bA = 2*tb;
  if(pA < POI)  { s[(size_t)bA*SCLD + pA]   = s00; s[(size_t)(bA+1)*SCLD + pA]   = s01; }
  if(pA+1 < POI){ s[(size_t)bA*SCLD + pA+1] = s10; s[(size_t)(bA+1)*SCLD + pA+1] = s11; }
}

// ---- per-b: a = sum_y sc_y; weight = exp2(-2*L2E*a) (tanh identity, SW cancels, bounded);
// normalize into slab0; zero pad; zero outc ctx region. grid 64, 1024 thr.
__global__ __launch_bounds__(1024) void k_softmax(float* __restrict__ sc, float* __restrict__ outc){
  __shared__ float red[1024];
  int b = blockIdx.x, t = threadIdx.x;
  if(t < 256) outc[b*KCAT + t] = 0.f;        // zero ctx accumulator region
  float* sA = sc + (size_t)b*SCLD;
  float sum = 0.f;
  for(int p=t;p<POI;p+=1024){
    float a = sA[p];
#pragma unroll
    for(int y=1;y<NSPL;y++) a += sA[(size_t)y*BB*SCLD + p];
    float wv = exp2_(-2.f*L2E*a);
    sA[p] = wv;
    sum += wv;
  }
  red[t] = sum; __syncthreads();
  for(int o=512;o>0;o>>=1){ if(t<o) red[t]+=red[t+o]; __syncthreads(); }
  float iv = rcp_(red[0]);
  for(int p=t;p<POI;p+=1024) sA[p] *= iv;    // normalized attention weights
  if(t < SCLD-POI) sA[POI + t] = 0.f;        // zero k-pad for ctx GEMM
}

// ---- context = wb[64,5024] @ emb[5000,256] (split-K x13, atomic) -> outc[:,0:256]
__global__ __launch_bounds__(256) void k_ctx(const float* __restrict__ wb, const float* __restrict__ emb,
                                             float* __restrict__ outc){
  int lane = threadIdx.x & 63, w = threadIdx.x >> 6;
  int n = blockIdx.x*16 + (lane & 15);       // n < 256
  int ky = blockIdx.y;                        // 13 splits of 384
  int kbeg = ky*384;
  int mr = w*16 + (lane & 15);
  f32x4 acc = mm16f(wb + kbeg, emb + (size_t)kbeg*EMB, SCLD, EMB, 384, mr, n, lane);
  if(ky == 12){                               // tail [4992,5024): wb pad=0, emb row clamped
    int q = lane >> 4;
    const float* ap = wb + (size_t)mr*SCLD + 4992 + q*8;
    bf16x8 a, bfr;
#pragma unroll
    for(int j=0;j<8;j++) a[j] = (bf16)ap[j];
#pragma unroll
    for(int j=0;j<8;j++){
      int k = 4992 + q*8 + j; int kc = k < POI ? k : POI-1;
      bfr[j] = (bf16)emb[(size_t)kc*EMB + n];
    }
    acc = __builtin_amdgcn_mfma_f32_16x16x32_bf16(a, bfr, acc, 0, 0, 0);
  }
  int rb = w*16 + (lane >> 4)*4;
#pragma unroll
  for(int r=0;r<4;r++) atomicAdd(&outc[(size_t)(rb+r)*KCAT + n], acc[r]);
}

// ---- logits: split-K x4, atomicAdd into d_out (zeroed by k_gates); bias in split 0. grid (313,4).
__global__ __launch_bounds__(256) void k_logits(const float* __restrict__ A, const float* __restrict__ Bw,
                        const float* __restrict__ fcb, float* __restrict__ out){
  int lane = threadIdx.x & 63, w = threadIdx.x >> 6;
  int n = blockIdx.x*16 + (lane & 15);
  int nc = n < POI ? n : POI-1;
  int ky = blockIdx.y, kbeg = ky*320;         // 4 x 320 = 1280
  f32x4 acc = mm16f(A + kbeg, Bw + (size_t)kbeg*POI, KCAT, POI, 320,
                    w*16 + (lane & 15), nc, lane);
  int rb = w*16 + (lane >> 4)*4;
  if(n < POI){
    float bn = (ky == 0) ? fcb[n] : 0.f;
#pragma unroll
    for(int r=0;r<4;r++) atomicAdd(&out[(size_t)(rb+r)*POI + n], acc[r] + bn);
  }
}

extern "C" void kernel_launch(void* const* d_in, const int* in_sizes, int n_in,
                              void* d_out, int out_size, void* d_ws, size_t ws_size,
                              hipStream_t stream){
  const int*   x     = (const int*)d_in[0];
  const float* query = (const float*)d_in[1];
  const float* emb   = (const float*)d_in[2];
  // d_in[3] A_hat unused by reference
  const float* h0    = (const float*)d_in[4];
  const float* catd  = (const float*)d_in[5];
  const float* gruK  = (const float*)d_in[6];
  const float* gruR  = (const float*)d_in[7];
  const float* gruB  = (const float*)d_in[8];
  const float* W1    = (const float*)d_in[9];
  const float* W1b   = (const float*)d_in[10];
  const float* W2    = (const float*)d_in[11];
  const float* W2b   = (const float*)d_in[12];
  const float* Vw    = (const float*)d_in[13];
  // d_in[14] V_b: softmax-invariant, dropped
  const float* fcw   = (const float*)d_in[15];
  const float* fcb   = (const float*)d_in[16];
  float* out = (float*)d_out;

  char* ws = (char*)d_ws;
  size_t off = 0;
  auto alloc = [&](size_t bytes)->void*{ void* p = ws + off; off += (bytes + 255) & ~(size_t)255; return p; };
  float* outc = (float*)alloc((size_t)BB*KCAT*4);
  float* xmP  = (float*)alloc((size_t)2*BB*1536*4);
  float* hmP  = (float*)alloc((size_t)2*BB*1536*4);
  float* hn   = (float*)alloc((size_t)BB*512*4);
  float* Eq   = (float*)alloc((size_t)BB*512*4);
  float* sc   = (float*)alloc((size_t)NSPL*BB*SCLD*4);   // 8 u-eighth slabs
  // total ~12 MB (R4 used 7.5 MB fine; ws re-poisoned to 0xAA, all buffers fully written before read)

  k_gru    <<<dim3(96,2,2), 256, 0, stream>>>(x, query, emb, h0, gruK, gruR, xmP, hmP);
  k_gates  <<<BB, 512, 0, stream>>>(xmP, hmP, gruB, h0, catd, hn, outc, out);
  k_qproj  <<<128, 64, 0, stream>>>(hn, W2, W2b, Eq);
  k_vscore <<<dim3(313,NSPL), 256, 0, stream>>>(emb, W1, W1b, Eq, Vw, sc);
  k_softmax<<<BB, 1024, 0, stream>>>(sc, outc);
  k_ctx    <<<dim3(16,13), 256, 0, stream>>>(sc, emb, outc);
  k_logits <<<dim3(313,4), 256, 0, stream>>>(outc, fcw, fcb, out);
}

// Round 8
// 214.508 us; speedup vs baseline: 1.1103x; 1.1103x over previous
//
#include <hip/hip_runtime.h>
#include <hip/hip_bf16.h>

typedef __bf16 bf16;
typedef __bf16 bf16x4 __attribute__((ext_vector_type(4)));
typedef __bf16 bf16x8 __attribute__((ext_vector_type(8)));
typedef float f32x4 __attribute__((ext_vector_type(4)));

#define BB 64
#define EMB 256
#define UNITS 512
#define POI 5000
#define KCAT 1280
#define SCLD 5024   // sc row stride (5000 padded to x32)
#define LGLD 5008   // logits slab row stride
#define L2E 1.4426950408889634f

__device__ __forceinline__ float rcp_(float x){ return __builtin_amdgcn_rcpf(x); }
__device__ __forceinline__ float exp2_(float x){ return __builtin_amdgcn_exp2f(x); }

// ---- 16x16 MFMA C-tile: A fp32 row-major (cvt->bf16), B pre-transposed bf16 Bt[n][k].
// B-fragment B[k=q*8+j][n] == Bt[n][q*8+j] -> one contiguous 16B load. C/D: col=lane&15, row=q*4+reg.
__device__ __forceinline__ f32x4 mm16bt(const float* __restrict__ A, const bf16* __restrict__ Bt,
                                        int lda, int ldbk, int K, int mr, int nc,
                                        int ka, int kb, int lane){
  int q = lane >> 4;
  f32x4 acc = {0.f,0.f,0.f,0.f};
  const float* ap = A + (size_t)mr*lda + ka + q*8;
  const bf16* bp = Bt + (size_t)nc*ldbk + kb + q*8;
#pragma unroll 2
  for(int k0 = 0; k0 < K; k0 += 32){
    f32x4 a0 = *(const f32x4*)ap;
    f32x4 a1 = *(const f32x4*)(ap+4);
    bf16x8 a;
#pragma unroll
    for(int j=0;j<4;j++){ a[j] = (bf16)a0[j]; a[4+j] = (bf16)a1[j]; }
    bf16x8 b = *(const bf16x8*)bp;
    acc = __builtin_amdgcn_mfma_f32_16x16x32_bf16(a, b, acc, 0, 0, 0);
    ap += 32; bp += 32;
  }
  return acc;
}

// ---- transpose+cvt all GEMM B-matrices to bf16 [N][K] layout. 64x64 tiles, 256 thr.
__global__ __launch_bounds__(256) void k_tr(const float* __restrict__ fcw, const float* __restrict__ gruK,
    const float* __restrict__ gruR, const float* __restrict__ W1, const float* __restrict__ W2,
    const float* __restrict__ emb, bf16* __restrict__ fcwT, bf16* __restrict__ gKT,
    bf16* __restrict__ gRT, bf16* __restrict__ W1T, bf16* __restrict__ W2T, bf16* __restrict__ embT){
  __shared__ float ls[64][65];
  int bid = blockIdx.x, t = threadIdx.x;
  const float* src; bf16* dst; int Ks, Ns, lddst, dRows, tn, tk;
  if(bid < 1580){      src=fcw;  Ks=1280; Ns=5000; dst=fcwT; lddst=1280; dRows=5008; tn=bid/20; tk=bid%20; }
  else if(bid < 1772){ int b=bid-1580; src=gruK; Ks=512; Ns=1536; dst=gKT; lddst=512; dRows=1536; tn=b/8; tk=b%8; }
  else if(bid < 1964){ int b=bid-1772; src=gruR; Ks=512; Ns=1536; dst=gRT; lddst=512; dRows=1536; tn=b/8; tk=b%8; }
  else if(bid < 1996){ int b=bid-1964; src=W1;   Ks=256; Ns=512;  dst=W1T; lddst=256; dRows=512;  tn=b/4; tk=b%4; }
  else if(bid < 2060){ int b=bid-1996; src=W2;   Ks=512; Ns=512;  dst=W2T; lddst=512; dRows=512;  tn=b/8; tk=b%8; }
  else {               int b=bid-2060; src=emb;  Ks=5000; Ns=256; dst=embT; lddst=5056; dRows=256; tn=b/79; tk=b%79; }
  int n0 = tn*64, k0 = tk*64;
  bool fullN = (n0 + 64 <= Ns);
#pragma unroll
  for(int ps=0; ps<4; ps++){
    int r = (t>>4) + ps*16;
    int sr = k0 + r; if(sr > Ks-1) sr = Ks-1;
    int c4 = (t&15)*4;
    if(fullN){
      f32x4 v = *(const f32x4*)&src[(size_t)sr*Ns + n0 + c4];
      ls[r][c4]=v[0]; ls[r][c4+1]=v[1]; ls[r][c4+2]=v[2]; ls[r][c4+3]=v[3];
    } else {
#pragma unroll
      for(int i=0;i<4;i++){ int sc2 = n0+c4+i; if(sc2 > Ns-1) sc2 = Ns-1; ls[r][c4+i] = src[(size_t)sr*Ns + sc2]; }
    }
  }
  __syncthreads();
#pragma unroll
  for(int ps=0; ps<4; ps++){
    int rr = (t>>4) + ps*16;
    int dr = n0 + rr;
    if(dr < dRows){
      int cc = (t&15)*4;
      bf16x4 o;
#pragma unroll
      for(int i=0;i<4;i++) o[i] = (bf16)ls[cc+i][rr];
      *(bf16x4*)&dst[(size_t)dr*lddst + k0 + cc] = o;
    }
  }
}

// ---- merged GRU GEMMs, split-K x2, x1 gather inlined. grid (96, 2, 2).
__global__ __launch_bounds__(256) void k_gru(const int* __restrict__ x,
    const float* __restrict__ query, const float* __restrict__ emb, const float* __restrict__ h0,
    const bf16* __restrict__ gKT, const bf16* __restrict__ gRT,
    float* __restrict__ xmP, float* __restrict__ hmP){
  int lane = threadIdx.x & 63, w = threadIdx.x >> 6;
  int col = blockIdx.x*16 + (lane & 15);
  int m = w*16 + (lane & 15);
  int z = blockIdx.z;
  const float* A; const bf16* Bt; int lda, mr, ka;
  if(blockIdx.y == 0){
    Bt = gKT;
    if(z == 0){ A = emb;   mr = x[m]; lda = EMB; ka = 0; }
    else      { A = query; mr = m;    lda = 256; ka = 0; }
  } else {
    Bt = gRT; A = h0; mr = m; lda = UNITS; ka = z*256;
  }
  f32x4 acc = mm16bt(A, Bt, lda, 512, 256, mr, col, ka, z*256, lane);
  float* C = (blockIdx.y ? hmP : xmP) + (size_t)z*BB*1536;
  int rb = w*16 + (lane >> 4)*4;
#pragma unroll
  for(int r=0;r<4;r++) C[(size_t)(rb+r)*1536 + col] = acc[r];
}

// ---- GRU gates (keras reset_after=True, z/r/h); sums 2 k-split slabs; copies cat_dec.
__global__ void k_gates(const float* __restrict__ xmP, const float* __restrict__ hmP,
                        const float* __restrict__ bias, const float* __restrict__ h0,
                        const float* __restrict__ catd,
                        float* __restrict__ hn, float* __restrict__ outc, float* __restrict__ dout){
  int b = blockIdx.x, u = threadIdx.x;  // 512 thr
  const float* x0 = xmP + b*1536; const float* x1s = xmP + (size_t)BB*1536 + b*1536;
  const float* h0s = hmP + b*1536; const float* h1s = hmP + (size_t)BB*1536 + b*1536;
  float xz = x0[u]      + x1s[u]      + bias[u];
  float xg = x0[512+u]  + x1s[512+u]  + bias[512+u];
  float xh = x0[1024+u] + x1s[1024+u] + bias[1024+u];
  float hz = h0s[u]      + h1s[u]      + bias[1536+u];
  float hg = h0s[512+u]  + h1s[512+u]  + bias[2048+u];
  float hh = h0s[1024+u] + h1s[1024+u] + bias[2560+u];
  float z = rcp_(1.f + exp2_(-L2E*(xz+hz)));
  float r = rcp_(1.f + exp2_(-L2E*(xg+hg)));
  float ca = xh + r*hh;
  ca = fminf(fmaxf(ca, -15.f), 15.f);
  float e = exp2_(2.f*L2E*ca);
  float hc = (e - 1.f)*rcp_(e + 1.f);
  float h = h0[b*512+u];
  float v = z*h + (1.f - z)*hc;
  hn[b*512+u] = v;
  outc[b*KCAT + 256 + u] = v;
  outc[b*KCAT + 768 + u] = catd[(size_t)b*512 + u];
  dout[(size_t)POI*BB + (size_t)b*512 + u] = v;                       // state
  dout[(size_t)POI*BB + (size_t)BB*512 + (size_t)b*512 + u] = v;      // output_
}

// ---- Eq = exp2(clamp(2*log2e*(hn@W2 + b2), +-28)) : [64,512]. grid 128 x 64thr.
__global__ __launch_bounds__(64) void k_qproj(const float* __restrict__ hn, const bf16* __restrict__ W2T,
                        const float* __restrict__ W2b, float* __restrict__ Eq){
  int lane = threadIdx.x;
  int m0 = (blockIdx.x & 3)*16;
  int col = (blockIdx.x >> 2)*16 + (lane & 15);
  f32x4 acc = mm16bt(hn, W2T, UNITS, UNITS, UNITS, m0 + (lane & 15), col, 0, 0, lane);
  float bn = W2b[col];
  int rb = m0 + (lane >> 4)*4;
#pragma unroll
  for(int r=0;r<4;r++){
    float v = (acc[r] + bn)*(2.f*L2E);
    Eq[(rb+r)*UNITS + col] = exp2_(fminf(fmaxf(v, -28.f), 28.f));
  }
}

// ---- fused vproj+score. EXACT R5 structure (44-VGPR proven): grid (313,4),
// 16 poi rows x 128-u quarter, c-loop 2x64u with double barrier (bounds LDS-load hoisting).
// Only change vs R5: stage-1 B from W1T (bf16 vector load).
__global__ __launch_bounds__(256) void k_vscore(const float* __restrict__ emb, const bf16* __restrict__ W1T,
    const float* __restrict__ W1b, const float* __restrict__ Eq,
    const float* __restrict__ Vw, float* __restrict__ scS){
  __shared__ float evs[16][132];
  __shared__ float Qs[64][68];
  __shared__ float vws[128];
  int t = threadIdx.x, lane = t & 63, w = t >> 6;
  int p0 = blockIdx.x*16, uh = blockIdx.y*128;
  int mr = p0 + (lane & 15); if(mr > POI-1) mr = POI-1;   // tail clamp
#pragma unroll
  for(int i=0;i<2;i++){
    int ncl = (w + i*4)*16 + (lane & 15);                  // local col 0..127
    f32x4 acc = mm16bt(emb, W1T, EMB, EMB, EMB, mr, uh + ncl, 0, 0, lane);
    float bn = W1b[uh + ncl];
    int rb = (lane >> 4)*4;
#pragma unroll
    for(int r=0;r<4;r++){
      float v = (acc[r] + bn)*(2.f*L2E);
      evs[rb+r][ncl] = exp2_(fminf(fmaxf(v, -28.f), 28.f));
    }
  }
  if(t < 128) vws[t] = Vw[uh + t];
  int tp = t & 7, tb = t >> 3;
  float s00=0.f, s01=0.f, s10=0.f, s11=0.f;
  for(int c=0;c<2;c++){
    __syncthreads();                 // c=0: evs/vws complete; c=1: Qs consumers done
    int ub = c*64;
    for(int i=t;i<4096;i+=256){ int b=i>>6, u=i&63; Qs[b][u] = Eq[b*UNITS + uh + ub + u]; }
    __syncthreads();
#pragma unroll
    for(int u4=0;u4<16;u4++){
      f32x4 e0 = *(f32x4*)&evs[2*tp][ub+u4*4];
      f32x4 e1 = *(f32x4*)&evs[2*tp+1][ub+u4*4];
      f32x4 q0 = *(f32x4*)&Qs[2*tb][u4*4];
      f32x4 q1 = *(f32x4*)&Qs[2*tb+1][u4*4];
      f32x4 w4 = *(f32x4*)&vws[ub+u4*4];
#pragma unroll
      for(int e=0;e<4;e++){
        float wv = w4[e];
        s00 += wv * rcp_(e0[e]*q0[e] + 1.f);
        s01 += wv * rcp_(e0[e]*q1[e] + 1.f);
        s10 += wv * rcp_(e1[e]*q0[e] + 1.f);
        s11 += wv * rcp_(e1[e]*q1[e] + 1.f);
      }
    }
  }
  float* s = scS + (size_t)blockIdx.y*BB*SCLD;
  int pA = p0 + 2*tp, bA = 2*tb;
  if(pA < POI)  { s[(size_t)bA*SCLD + pA]   = s00; s[(size_t)(bA+1)*SCLD + pA]   = s01; }
  if(pA+1 < POI){ s[(size_t)bA*SCLD + pA+1] = s10; s[(size_t)(bA+1)*SCLD + pA+1] = s11; }
}

// ---- per-b: a = sum_y sc_y; w = exp2(-2*L2E*a) (tanh identity, SW cancels, bounded);
// normalize into slab0; zero pad; zero outc ctx region. grid 64, 1024 thr.
__global__ __launch_bounds__(1024) void k_softmax(float* __restrict__ sc, float* __restrict__ outc){
  __shared__ float red[1024];
  int b = blockIdx.x, t = threadIdx.x;
  if(t < 256) outc[b*KCAT + t] = 0.f;        // zero ctx accumulator region
  float* sA = sc + (size_t)b*SCLD;
  float sum = 0.f;
  for(int p=t;p<POI;p+=1024){
    float a = sA[p] + sA[(size_t)BB*SCLD + p] + sA[(size_t)2*BB*SCLD + p] + sA[(size_t)3*BB*SCLD + p];
    float wv = exp2_(-2.f*L2E*a);
    sA[p] = wv;
    sum += wv;
  }
  red[t] = sum; __syncthreads();
  for(int o=512;o>0;o>>=1){ if(t<o) red[t]+=red[t+o]; __syncthreads(); }
  float iv = rcp_(red[0]);
  for(int p=t;p<POI;p+=1024) sA[p] *= iv;    // normalized attention weights
  if(t < SCLD-POI) sA[POI + t] = 0.f;        // zero k-pad for ctx GEMM
}

// ---- context = wb[64,5024] @ emb (via embT bf16) -> outc[:,0:256]. grid (16,13), atomics.
// splits 0..11: K=384; split 12: K=416 (covers 5024; wb pad rows zero out embT's clamped tail).
__global__ __launch_bounds__(256) void k_ctx(const float* __restrict__ wb, const bf16* __restrict__ embT,
                                             float* __restrict__ outc){
  int lane = threadIdx.x & 63, w = threadIdx.x >> 6;
  int n = blockIdx.x*16 + (lane & 15);       // n < 256
  int ky = blockIdx.y;
  int kbeg = ky*384, kk = (ky == 12) ? 416 : 384;
  f32x4 acc = mm16bt(wb, embT, SCLD, 5056, kk, w*16 + (lane & 15), n, kbeg, kbeg, lane);
  int rb = w*16 + (lane >> 4)*4;
#pragma unroll
  for(int r=0;r<4;r++) atomicAdd(&outc[(size_t)(rb+r)*KCAT + n], acc[r]);
}

// ---- logits split-K x2 into fp32 slabs (no atomics). grid (313,2). n up to 5007 (fcwT padded).
__global__ __launch_bounds__(256) void k_logits(const float* __restrict__ A, const bf16* __restrict__ fcwT,
                                                float* __restrict__ lgP){
  int lane = threadIdx.x & 63, w = threadIdx.x >> 6;
  int n = blockIdx.x*16 + (lane & 15);
  int ky = blockIdx.y, kbeg = ky*640;
  f32x4 acc = mm16bt(A, fcwT, KCAT, 1280, 640, w*16 + (lane & 15), n, kbeg, kbeg, lane);
  float* dst = lgP + (size_t)ky*BB*SCLD;
  int rb = w*16 + (lane >> 4)*4;
#pragma unroll
  for(int r=0;r<4;r++) dst[(size_t)(rb+r)*LGLD + n] = acc[r];
}

// ---- out = lg0 + lg1 + fcb. grid 313 x 256 (exactly 64*5008/4 quads).
__global__ __launch_bounds__(256) void k_lred(const float* __restrict__ lgP, const float* __restrict__ fcb,
                                              float* __restrict__ out){
  int idx = blockIdx.x*256 + threadIdx.x;
  int m = idx / 1252, nq = idx % 1252;
  int n = nq*4;
  if(n < POI){
    f32x4 a = *(const f32x4*)&lgP[(size_t)m*LGLD + n];
    f32x4 b = *(const f32x4*)&lgP[(size_t)BB*SCLD + (size_t)m*LGLD + n];
    f32x4 c = *(const f32x4*)&fcb[n];
    f32x4 r = a + b + c;
    *(f32x4*)&out[(size_t)m*POI + n] = r;
  }
}

extern "C" void kernel_launch(void* const* d_in, const int* in_sizes, int n_in,
                              void* d_out, int out_size, void* d_ws, size_t ws_size,
                              hipStream_t stream){
  const int*   x     = (const int*)d_in[0];
  const float* query = (const float*)d_in[1];
  const float* emb   = (const float*)d_in[2];
  // d_in[3] A_hat unused by reference
  const float* h0    = (const float*)d_in[4];
  const float* catd  = (const float*)d_in[5];
  const float* gruK  = (const float*)d_in[6];
  const float* gruR  = (const float*)d_in[7];
  const float* gruB  = (const float*)d_in[8];
  const float* W1    = (const float*)d_in[9];
  const float* W1b   = (const float*)d_in[10];
  const float* W2    = (const float*)d_in[11];
  const float* W2b   = (const float*)d_in[12];
  const float* Vw    = (const float*)d_in[13];
  // d_in[14] V_b: softmax-invariant, dropped
  const float* fcw   = (const float*)d_in[15];
  const float* fcb   = (const float*)d_in[16];
  float* out = (float*)d_out;

  char* ws = (char*)d_ws;
  size_t off = 0;
  auto alloc = [&](size_t bytes)->void*{ void* p = ws + off; off += (bytes + 255) & ~(size_t)255; return p; };
  float* outc = (float*)alloc((size_t)BB*KCAT*4);
  float* xmP  = (float*)alloc((size_t)2*BB*1536*4);
  float* hmP  = (float*)alloc((size_t)2*BB*1536*4);
  float* hn   = (float*)alloc((size_t)BB*512*4);
  float* Eq   = (float*)alloc((size_t)BB*512*4);
  float* sc   = (float*)alloc((size_t)4*BB*SCLD*4);     // 4 u-quarter slabs; slabs 1-2 reused as logits partials
  bf16* fcwT  = (bf16*)alloc((size_t)5008*1280*2);
  bf16* gKT   = (bf16*)alloc((size_t)1536*512*2);
  bf16* gRT   = (bf16*)alloc((size_t)1536*512*2);
  bf16* W1T   = (bf16*)alloc((size_t)512*256*2);
  bf16* W2T   = (bf16*)alloc((size_t)512*512*2);
  bf16* embT  = (bf16*)alloc((size_t)256*5056*2);
  float* lgP  = sc + (size_t)BB*SCLD;                   // logits slabs alias sc slabs 1-2 (dead after softmax)
  // total ~26.6 MB

  k_tr     <<<2376, 256, 0, stream>>>(fcw, gruK, gruR, W1, W2, emb, fcwT, gKT, gRT, W1T, W2T, embT);
  k_gru    <<<dim3(96,2,2), 256, 0, stream>>>(x, query, emb, h0, gKT, gRT, xmP, hmP);
  k_gates  <<<BB, 512, 0, stream>>>(xmP, hmP, gruB, h0, catd, hn, outc, out);
  k_qproj  <<<128, 64, 0, stream>>>(hn, W2T, W2b, Eq);
  k_vscore <<<dim3(313,4), 256, 0, stream>>>(emb, W1T, W1b, Eq, Vw, sc);
  k_softmax<<<BB, 1024, 0, stream>>>(sc, outc);
  k_ctx    <<<dim3(16,13), 256, 0, stream>>>(sc, embT, outc);
  k_logits <<<dim3(313,2), 256, 0, stream>>>(outc, fcwT, lgP);
  k_lred   <<<313, 256, 0, stream>>>(lgP, fcb, out);
}